// Round 4
// baseline (142.955 us; speedup 1.0000x reference)
//
#include <hip/hip_runtime.h>

#define NN 8192
#define BB 32
#define EMB 16
#define HID 64
#define MS 16           // m-range splits
#define TM 64           // m per tile
#define VT_PITCH 8224   // bf16 elems per VT row (16448 B: breaks 16KB L2-set aliasing)

typedef __attribute__((ext_vector_type(8))) short bf16x8;
typedef __attribute__((ext_vector_type(4))) float f32x4;

static __device__ inline short f2b(float f) {           // round-to-nearest-even
    union { float f; unsigned u; } v; v.f = f;
    unsigned r = (v.u + 0x7fffu + ((v.u >> 16) & 1u)) >> 16;
    return (short)r;
}

// ---------------------------------------------------------------------------
// K1: fused operand prep.
//  blocks [0,512):    VT[j][m] = bf16(x[b=j>>1][m][c=j&1])
//  blocks [512,640):  adjB = bf16(adj), adjS = bf16(adj*log2e)
//  blocks [640,1152): Wbuf[n][c*64+o] (node-adaptive weights+bias, c={x0,x1,y0,y1,b})
// ---------------------------------------------------------------------------
__global__ void k_build(const float* __restrict__ x, const float* __restrict__ adj,
                        const float* __restrict__ wp, const float* __restrict__ bp,
                        short* __restrict__ VT, short* __restrict__ adjB,
                        short* __restrict__ adjS, float* __restrict__ Wbuf) {
    int t = threadIdx.x;
    if (blockIdx.x < 512) {
        int idx = blockIdx.x * 256 + t;          // 0 .. 131071
        int b = idx >> 12;
        int m = (idx & 4095) * 2;
        float4 xx = *(const float4*)(x + (size_t)b * NN * 2 + 2 * m);
        unsigned u0 = (unsigned short)f2b(xx.x) | ((unsigned)(unsigned short)f2b(xx.z) << 16);
        unsigned u1 = (unsigned short)f2b(xx.y) | ((unsigned)(unsigned short)f2b(xx.w) << 16);
        *(unsigned*)(VT + (size_t)(2 * b) * VT_PITCH + m) = u0;
        *(unsigned*)(VT + (size_t)(2 * b + 1) * VT_PITCH + m) = u1;
    } else if (blockIdx.x < 640) {
        const float L2E = 1.4426950408889634f;
        int idx = (blockIdx.x - 512) * 256 + t;   // 0 .. 32767
        float4 aa = *(const float4*)(adj + (size_t)idx * 4);
        uint2 ub, us;
        ub.x = (unsigned short)f2b(aa.x) | ((unsigned)(unsigned short)f2b(aa.y) << 16);
        ub.y = (unsigned short)f2b(aa.z) | ((unsigned)(unsigned short)f2b(aa.w) << 16);
        us.x = (unsigned short)f2b(aa.x * L2E) | ((unsigned)(unsigned short)f2b(aa.y * L2E) << 16);
        us.y = (unsigned short)f2b(aa.z * L2E) | ((unsigned)(unsigned short)f2b(aa.w * L2E) << 16);
        *(uint2*)(adjB + (size_t)idx * 4) = ub;
        *(uint2*)(adjS + (size_t)idx * 4) = us;
    } else {
        const int nl = t >> 4, og = t & 15;
        const int n = (blockIdx.x - 640) * 16 + nl;
        const float4* wp4 = (const float4*)wp;
        const float4* bp4 = (const float4*)bp;
        float an[EMB];
#pragma unroll
        for (int d = 0; d < EMB; ++d) an[d] = adj[n * EMB + d];
        float4 w[5];
#pragma unroll
        for (int c = 0; c < 5; ++c) { w[c].x = w[c].y = w[c].z = w[c].w = 0.f; }
#pragma unroll
        for (int d = 0; d < EMB; ++d) {
            float a = an[d];
#pragma unroll
            for (int c = 0; c < 4; ++c) {
                float4 p = wp4[(d * 4 + c) * 16 + og];
                w[c].x += a * p.x; w[c].y += a * p.y; w[c].z += a * p.z; w[c].w += a * p.w;
            }
            float4 pb = bp4[d * 16 + og];
            w[4].x += a * pb.x; w[4].y += a * pb.y; w[4].z += a * pb.z; w[4].w += a * pb.w;
        }
#pragma unroll
        for (int c = 0; c < 5; ++c)
            *(float4*)(Wbuf + (size_t)n * 320 + c * 64 + og * 4) = w[c];
    }
}

// ---------------------------------------------------------------------------
// K2: barrier-free MFMA flash propagation. Block = 256 thr = 4 waves, each
// wave owns 32 n and the block's m-chunk (NN/MS). ~110 VGPR -> 4 waves/SIMD.
// Partials: ynum bf16 [split][n][64], den f32 [split][n]. No LDS, no atomics.
// ---------------------------------------------------------------------------
__launch_bounds__(256, 4)
__global__ void k_prop(const short* __restrict__ adjB, const short* __restrict__ adjS,
                       const short* __restrict__ VT,
                       short* __restrict__ ynum, float* __restrict__ den) {
    const int t = threadIdx.x;
    const int wv = t >> 6;
    const int lane = t & 63;
    const int l = lane & 15;
    const int q = lane >> 4;
    const int n0 = blockIdx.x * 128 + wv * 32;
    const int mbeg = blockIdx.y * (NN / MS);

    // score B-fragments: 2 x 16 n-rows (log2e-scaled side), k>=16 zeroed
    bf16x8 Bn[2];
    bf16x8 zv = {0, 0, 0, 0, 0, 0, 0, 0};
#pragma unroll
    for (int s = 0; s < 2; ++s) {
        const short* src = adjS + (size_t)(n0 + 16 * s + l) * EMB + (q & 1) * 8;
        bf16x8 v = *(const bf16x8*)src;
        Bn[s] = (q < 2) ? v : zv;
    }

    f32x4 acc[4][2];   // [u][s] : O^T rows 16u+4q+r, cols n0+16s+l
#pragma unroll
    for (int u = 0; u < 4; ++u)
#pragma unroll
        for (int s = 0; s < 2; ++s) { acc[u][s][0] = acc[u][s][1] = acc[u][s][2] = acc[u][s][3] = 0.f; }
    float dsum[2] = {0.f, 0.f};

    const int mrow_b = 8 * (l >> 2) + (l & 3);   // permuted A-row base

    for (int m0 = mbeg; m0 < mbeg + (NN / MS); m0 += TM) {
#pragma unroll
        for (int c = 0; c < 2; ++c) {
            const int mc = m0 + 32 * c;
            bf16x8 Af0 = *(const bf16x8*)(adjB + (size_t)(mc + mrow_b + 0) * EMB + (q & 1) * 8);
            bf16x8 Af1 = *(const bf16x8*)(adjB + (size_t)(mc + mrow_b + 4) * EMB + (q & 1) * 8);
            bf16x8 Vf[4];
#pragma unroll
            for (int u = 0; u < 4; ++u)
                Vf[u] = *(const bf16x8*)(VT + (size_t)(16 * u + l) * VT_PITCH + mc + q * 8);

            f32x4 z = {0.f, 0.f, 0.f, 0.f};
            f32x4 S0[2], S1[2];
#pragma unroll
            for (int s = 0; s < 2; ++s) {
                S0[s] = __builtin_amdgcn_mfma_f32_16x16x32_bf16(Af0, Bn[s], z, 0, 0, 0);
                S1[s] = __builtin_amdgcn_mfma_f32_16x16x32_bf16(Af1, Bn[s], z, 0, 0, 0);
            }
#pragma unroll
            for (int s = 0; s < 2; ++s) {
                unsigned wb[8];
#pragma unroll
                for (int r = 0; r < 4; ++r) {
                    union { float f; unsigned u; } p0, p1;
                    p0.f = __builtin_amdgcn_exp2f(fmaxf(S0[s][r], 0.f));
                    p1.f = __builtin_amdgcn_exp2f(fmaxf(S1[s][r], 0.f));
                    dsum[s] += p0.f + p1.f;
                    wb[r] = p0.u;        // j = r      (h=0)
                    wb[4 + r] = p1.u;    // j = 4 + r  (h=1)
                }
                union { bf16x8 v; unsigned d[4]; } pf;
#pragma unroll
                for (int dd = 0; dd < 4; ++dd)
                    pf.d[dd] = (wb[2 * dd + 1] & 0xFFFF0000u) | (wb[2 * dd] >> 16);  // trunc pack
#pragma unroll
                for (int u = 0; u < 4; ++u)
                    acc[u][s] = __builtin_amdgcn_mfma_f32_16x16x32_bf16(Vf[u], pf.v, acc[u][s], 0, 0, 0);
            }
        }
    }

    // stores: bf16 partials [split][n][64]; den via cross-quad shfl reduce
    short* yp = ynum + (size_t)blockIdx.y * NN * HID;
#pragma unroll
    for (int s = 0; s < 2; ++s) {
        const int n = n0 + 16 * s + l;
#pragma unroll
        for (int u = 0; u < 4; ++u) {
            union { float f; unsigned u; } a0, a1, a2, a3;
            a0.f = acc[u][s][0]; a1.f = acc[u][s][1]; a2.f = acc[u][s][2]; a3.f = acc[u][s][3];
            uint2 pk;
            pk.x = (a1.u & 0xFFFF0000u) | (a0.u >> 16);
            pk.y = (a3.u & 0xFFFF0000u) | (a2.u >> 16);
            *(uint2*)(yp + (size_t)n * HID + 16 * u + 4 * q) = pk;
        }
        float d = dsum[s];
        d += __shfl_xor(d, 16);
        d += __shfl_xor(d, 32);
        if (q == 0) den[(size_t)blockIdx.y * NN + n] = d;
    }
}

// ---------------------------------------------------------------------------
// K3: epilogue. 16 nodes/block; reduce MS bf16 partials, normalize, apply
// precomputed per-node weights, write out [32][8192][64] fp32.
// ---------------------------------------------------------------------------
__global__ void k_epi(const float* __restrict__ Wbuf, const float* __restrict__ x,
                      const short* __restrict__ ynum, const float* __restrict__ den,
                      float* __restrict__ out) {
    const int nl = threadIdx.x >> 4, og = threadIdx.x & 15;
    const int n = blockIdx.x * 16 + nl;
    __shared__ float xl[16][68];
    __shared__ float yl[16][68];

    float4 W[5];
#pragma unroll
    for (int c = 0; c < 5; ++c)
        W[c] = *(const float4*)(Wbuf + (size_t)n * 320 + c * 64 + og * 4);

    float4 ysum; ysum.x = ysum.y = ysum.z = ysum.w = 0.f;
    float dsum = 0.f;
#pragma unroll
    for (int s = 0; s < MS; ++s) {
        ushort4 p = *(const ushort4*)(ynum + ((size_t)s * NN + n) * HID + og * 4);
        union { unsigned u; float f; } c0, c1, c2, c3;
        c0.u = (unsigned)p.x << 16; c1.u = (unsigned)p.y << 16;
        c2.u = (unsigned)p.z << 16; c3.u = (unsigned)p.w << 16;
        ysum.x += c0.f; ysum.y += c1.f; ysum.z += c2.f; ysum.w += c3.f;
        dsum += den[(size_t)s * NN + n];
    }
    float rden = 1.f / dsum;
    *(float4*)&yl[nl][og * 4] = make_float4(ysum.x * rden, ysum.y * rden, ysum.z * rden, ysum.w * rden);

    float2 x0 = *(const float2*)(x + ((size_t)(og * 2) * NN + n) * 2);
    float2 x1 = *(const float2*)(x + ((size_t)(og * 2 + 1) * NN + n) * 2);
    xl[nl][og * 4 + 0] = x0.x; xl[nl][og * 4 + 1] = x0.y;
    xl[nl][og * 4 + 2] = x1.x; xl[nl][og * 4 + 3] = x1.y;
    __syncthreads();

#pragma unroll 4
    for (int b = 0; b < BB; ++b) {
        float xb0 = xl[nl][2 * b], xb1 = xl[nl][2 * b + 1];
        float yb0 = yl[nl][2 * b], yb1 = yl[nl][2 * b + 1];
        float4 o4;
        o4.x = xb0 * W[0].x + xb1 * W[1].x + yb0 * W[2].x + yb1 * W[3].x + W[4].x;
        o4.y = xb0 * W[0].y + xb1 * W[1].y + yb0 * W[2].y + yb1 * W[3].y + W[4].y;
        o4.z = xb0 * W[0].z + xb1 * W[1].z + yb0 * W[2].z + yb1 * W[3].z + W[4].z;
        o4.w = xb0 * W[0].w + xb1 * W[1].w + yb0 * W[2].w + yb1 * W[3].w + W[4].w;
        *(float4*)(out + ((size_t)b * NN + n) * HID + og * 4) = o4;
    }
}

// ---------------------------------------------------------------------------
extern "C" void kernel_launch(void* const* d_in, const int* in_sizes, int n_in,
                              void* d_out, int out_size, void* d_ws, size_t ws_size,
                              hipStream_t stream) {
    const float* x   = (const float*)d_in[0];   // [32, 8192, 2]
    const float* adj = (const float*)d_in[1];   // [8192, 16]
    const float* wp  = (const float*)d_in[2];   // [16, 2, 2, 64]
    const float* bp  = (const float*)d_in[3];   // [16, 64]
    float* out = (float*)d_out;                 // [32, 8192, 64]

    char* w = (char*)d_ws;
    short* VT   = (short*)w;                                     // 64*8224*2 ~= 1.05 MB
    short* adjB = (short*)(w + (size_t)2 * 64 * VT_PITCH);       // 256 KB
    short* adjS = adjB + (size_t)NN * EMB;                       // 256 KB
    float* Wbuf = (float*)(w + (size_t)2 * 64 * VT_PITCH + (size_t)4 * NN * EMB);  // 10.5 MB
    short* ynum = (short*)(Wbuf + (size_t)NN * 320);             // MS*N*64*2 = 16 MB
    float* den  = (float*)(ynum + (size_t)MS * NN * HID);        // 512 KB

    k_build<<<1152, 256, 0, stream>>>(x, adj, wp, bp, VT, adjB, adjS, Wbuf);
    k_prop<<<dim3(NN / 128, MS), 256, 0, stream>>>(adjB, adjS, VT, ynum, den);
    k_epi<<<NN / 16, 256, 0, stream>>>(Wbuf, x, ynum, den, out);
}

// Round 5
// 133.047 us; speedup vs baseline: 1.0745x; 1.0745x over previous
//
#include <hip/hip_runtime.h>

#define NN 8192
#define BB 32
#define EMB 16
#define HID 64
#define MS 16           // m-range splits
#define TM 64           // m per tile (2 MFMA c-subtiles of 32)

typedef __attribute__((ext_vector_type(8))) short bf16x8;
typedef __attribute__((ext_vector_type(4))) float f32x4;

static __device__ inline unsigned short f2b(float f) {   // round-to-nearest-even
    union { float f; unsigned u; } v; v.f = f;
    return (unsigned short)((v.u + 0x7fffu + ((v.u >> 16) & 1u)) >> 16);
}

// ---------------------------------------------------------------------------
// K1: fused operand prep, everything stored in MFMA-fragment lane order so
// k_prop's inner loads are sequential coalesced 1KB dwordx4 streams.
//  bx [0,256):    VTf[c][u][lane] : V-fragment (PV A-operand), c = m/32
//  bx [256,384):  Afrag[c][h][lane]: adj m-rows (score A-operand, permuted rows)
//  bx [384,512):  adjS[n][d] = bf16(adj*log2e)   (score B side, row-major)
//  bx [512,1024): Wbuf[n][c*64+o]  (node-adaptive weights+bias)
// ---------------------------------------------------------------------------
__global__ void k_build(const float* __restrict__ x, const float* __restrict__ adj,
                        const float* __restrict__ wp, const float* __restrict__ bp,
                        short* __restrict__ VTf, short* __restrict__ Afrag,
                        short* __restrict__ adjS, float* __restrict__ Wbuf) {
    const int t = threadIdx.x;
    const int bx = blockIdx.x;
    if (bx < 256) {
        // V[j][m] = x[b=j>>1][m][c=j&1];  fragment: lane(l,q) <- V[16u+l][32c+8q..+7]
        const int c = bx;
        const int u = t >> 6, lane = t & 63, l = lane & 15, q = lane >> 4;
        const int j = 16 * u + l, b = j >> 1, ch = j & 1;
        const int m0 = 32 * c + 8 * q;
        const float* xp = x + (size_t)b * (NN * 2) + m0 * 2;
        uint4 d;
        unsigned dd[4];
#pragma unroll
        for (int i = 0; i < 4; ++i) {
            float4 xx = *(const float4*)(xp + 4 * i);   // m0+2i (ch0,ch1), m0+2i+1 (ch0,ch1)
            float v0 = ch ? xx.y : xx.x;
            float v1 = ch ? xx.w : xx.z;
            dd[i] = (unsigned)f2b(v0) | ((unsigned)f2b(v1) << 16);
        }
        d.x = dd[0]; d.y = dd[1]; d.z = dd[2]; d.w = dd[3];
        *(uint4*)(VTf + ((size_t)(c * 4 + u) * 64 + lane) * 8) = d;
    } else if (bx < 384) {
        // Afrag: lane(l,q) <- adj[32c + 8*(l>>2)+(l&3) + 4h][(q&1)*8 ..+7]
        const int cc = t >> 7, tt = t & 127;
        const int c = (bx - 256) * 2 + cc;
        const int h = tt >> 6, lane = tt & 63, l = lane & 15, q = lane >> 4;
        const int row = 32 * c + 8 * (l >> 2) + (l & 3) + 4 * h;
        const float* ap = adj + (size_t)row * EMB + (q & 1) * 8;
        float4 a0 = *(const float4*)(ap);
        float4 a1 = *(const float4*)(ap + 4);
        uint4 d;
        d.x = (unsigned)f2b(a0.x) | ((unsigned)f2b(a0.y) << 16);
        d.y = (unsigned)f2b(a0.z) | ((unsigned)f2b(a0.w) << 16);
        d.z = (unsigned)f2b(a1.x) | ((unsigned)f2b(a1.y) << 16);
        d.w = (unsigned)f2b(a1.z) | ((unsigned)f2b(a1.w) << 16);
        *(uint4*)(Afrag + ((size_t)(c * 2 + h) * 64 + lane) * 8) = d;
    } else if (bx < 512) {
        const float L2E = 1.4426950408889634f;
        int idx = (bx - 384) * 256 + t;   // 0 .. 32767
        float4 aa = *(const float4*)(adj + (size_t)idx * 4);
        uint2 us;
        us.x = (unsigned)f2b(aa.x * L2E) | ((unsigned)f2b(aa.y * L2E) << 16);
        us.y = (unsigned)f2b(aa.z * L2E) | ((unsigned)f2b(aa.w * L2E) << 16);
        *(uint2*)(adjS + (size_t)idx * 4) = us;
    } else {
        const int nl = t >> 4, og = t & 15;
        const int n = (bx - 512) * 16 + nl;
        const float4* wp4 = (const float4*)wp;
        const float4* bp4 = (const float4*)bp;
        float an[EMB];
#pragma unroll
        for (int d = 0; d < EMB; ++d) an[d] = adj[n * EMB + d];
        float4 w[5];
#pragma unroll
        for (int c = 0; c < 5; ++c) { w[c].x = w[c].y = w[c].z = w[c].w = 0.f; }
#pragma unroll
        for (int d = 0; d < EMB; ++d) {
            float a = an[d];
#pragma unroll
            for (int c = 0; c < 4; ++c) {
                float4 p = wp4[(d * 4 + c) * 16 + og];
                w[c].x += a * p.x; w[c].y += a * p.y; w[c].z += a * p.z; w[c].w += a * p.w;
            }
            float4 pb = bp4[d * 16 + og];
            w[4].x += a * pb.x; w[4].y += a * pb.y; w[4].z += a * pb.z; w[4].w += a * pb.w;
        }
#pragma unroll
        for (int c = 0; c < 5; ++c)
            *(float4*)(Wbuf + (size_t)n * 320 + c * 64 + og * 4) = w[c];
    }
}

// ---------------------------------------------------------------------------
// K2: barrier-free MFMA flash propagation, all operands pre-swizzled so every
// load is a sequential coalesced 1KB stream. 4 waves/block, 32 n per wave.
// Denominator via all-ones MFMA (matrix pipe, not VALU). bf16 partial out.
// ---------------------------------------------------------------------------
__launch_bounds__(256, 4)
__global__ void k_prop(const short* __restrict__ Afrag, const short* __restrict__ adjS,
                       const short* __restrict__ VTf,
                       short* __restrict__ ynum, float* __restrict__ den) {
    const int t = threadIdx.x;
    const int wv = t >> 6;
    const int lane = t & 63;
    const int l = lane & 15;
    const int q = lane >> 4;
    const int n0 = blockIdx.x * 128 + wv * 32;
    const int cbeg = blockIdx.y * (NN / MS / 32);   // c-subtile index range
    const int cend = cbeg + (NN / MS / 32);

    // score B-fragments: 2 x 16 n-rows (log2e-scaled), k>=16 zeroed
    bf16x8 Bn[2];
    bf16x8 zv = {0, 0, 0, 0, 0, 0, 0, 0};
#pragma unroll
    for (int s = 0; s < 2; ++s) {
        const short* src = adjS + (size_t)(n0 + 16 * s + l) * EMB + (q & 1) * 8;
        bf16x8 v = *(const bf16x8*)src;
        Bn[s] = (q < 2) ? v : zv;
    }
    const short one = (short)0x3F80;
    bf16x8 ones = {one, one, one, one, one, one, one, one};

    f32x4 acc[4][2];   // [u][s] : O^T rows 16u+4q+r, cols n0+16s+l
    f32x4 dacc[2];
#pragma unroll
    for (int u = 0; u < 4; ++u)
#pragma unroll
        for (int s = 0; s < 2; ++s) { acc[u][s][0] = acc[u][s][1] = acc[u][s][2] = acc[u][s][3] = 0.f; }
#pragma unroll
    for (int s = 0; s < 2; ++s) { dacc[s][0] = dacc[s][1] = dacc[s][2] = dacc[s][3] = 0.f; }

    for (int cg = cbeg; cg < cend; ++cg) {
        // sequential coalesced fragment loads: 2x1KB (A) + 4x1KB (V)
        bf16x8 Af0 = *(const bf16x8*)(Afrag + ((size_t)(cg * 2 + 0) * 64 + lane) * 8);
        bf16x8 Af1 = *(const bf16x8*)(Afrag + ((size_t)(cg * 2 + 1) * 64 + lane) * 8);
        bf16x8 Vf[4];
#pragma unroll
        for (int u = 0; u < 4; ++u)
            Vf[u] = *(const bf16x8*)(VTf + ((size_t)(cg * 4 + u) * 64 + lane) * 8);

        f32x4 z = {0.f, 0.f, 0.f, 0.f};
        f32x4 S0[2], S1[2];
#pragma unroll
        for (int s = 0; s < 2; ++s) {
            S0[s] = __builtin_amdgcn_mfma_f32_16x16x32_bf16(Af0, Bn[s], z, 0, 0, 0);
            S1[s] = __builtin_amdgcn_mfma_f32_16x16x32_bf16(Af1, Bn[s], z, 0, 0, 0);
        }
#pragma unroll
        for (int s = 0; s < 2; ++s) {
            unsigned wb[8];
#pragma unroll
            for (int r = 0; r < 4; ++r) {
                union { float f; unsigned u; } p0, p1;
                p0.f = __builtin_amdgcn_exp2f(fmaxf(S0[s][r], 0.f));
                p1.f = __builtin_amdgcn_exp2f(fmaxf(S1[s][r], 0.f));
                wb[r] = p0.u;        // j = r      (h=0)
                wb[4 + r] = p1.u;    // j = 4 + r  (h=1)
            }
            union { bf16x8 v; unsigned d[4]; } pf;
#pragma unroll
            for (int dd = 0; dd < 4; ++dd)
                pf.d[dd] = (wb[2 * dd + 1] & 0xFFFF0000u) | (wb[2 * dd] >> 16);  // trunc pack
#pragma unroll
            for (int u = 0; u < 4; ++u)
                acc[u][s] = __builtin_amdgcn_mfma_f32_16x16x32_bf16(Vf[u], pf.v, acc[u][s], 0, 0, 0);
            dacc[s] = __builtin_amdgcn_mfma_f32_16x16x32_bf16(ones, pf.v, dacc[s], 0, 0, 0);
        }
    }

    // stores: bf16 partials [split][n][64]; den rows all equal -> dacc[s][0]
    short* yp = ynum + (size_t)blockIdx.y * NN * HID;
#pragma unroll
    for (int s = 0; s < 2; ++s) {
        const int n = n0 + 16 * s + l;
#pragma unroll
        for (int u = 0; u < 4; ++u) {
            union { float f; unsigned u; } a0, a1, a2, a3;
            a0.f = acc[u][s][0]; a1.f = acc[u][s][1]; a2.f = acc[u][s][2]; a3.f = acc[u][s][3];
            uint2 pk;
            pk.x = (a1.u & 0xFFFF0000u) | (a0.u >> 16);
            pk.y = (a3.u & 0xFFFF0000u) | (a2.u >> 16);
            *(uint2*)(yp + (size_t)n * HID + 16 * u + 4 * q) = pk;
        }
        if (q == 0) den[(size_t)blockIdx.y * NN + n] = dacc[s][0];
    }
}

// ---------------------------------------------------------------------------
// K3: epilogue. 16 nodes/block; reduce MS bf16 partials, normalize, apply
// precomputed per-node weights, write out [32][8192][64] fp32.
// ---------------------------------------------------------------------------
__global__ void k_epi(const float* __restrict__ Wbuf, const float* __restrict__ x,
                      const short* __restrict__ ynum, const float* __restrict__ den,
                      float* __restrict__ out) {
    const int nl = threadIdx.x >> 4, og = threadIdx.x & 15;
    const int n = blockIdx.x * 16 + nl;
    __shared__ float xl[16][68];
    __shared__ float yl[16][68];

    float4 W[5];
#pragma unroll
    for (int c = 0; c < 5; ++c)
        W[c] = *(const float4*)(Wbuf + (size_t)n * 320 + c * 64 + og * 4);

    float4 ysum; ysum.x = ysum.y = ysum.z = ysum.w = 0.f;
    float dsum = 0.f;
#pragma unroll
    for (int s = 0; s < MS; ++s) {
        ushort4 p = *(const ushort4*)(ynum + ((size_t)s * NN + n) * HID + og * 4);
        union { unsigned u; float f; } c0, c1, c2, c3;
        c0.u = (unsigned)p.x << 16; c1.u = (unsigned)p.y << 16;
        c2.u = (unsigned)p.z << 16; c3.u = (unsigned)p.w << 16;
        ysum.x += c0.f; ysum.y += c1.f; ysum.z += c2.f; ysum.w += c3.f;
        dsum += den[(size_t)s * NN + n];
    }
    float rden = 1.f / dsum;
    *(float4*)&yl[nl][og * 4] = make_float4(ysum.x * rden, ysum.y * rden, ysum.z * rden, ysum.w * rden);

    float2 x0 = *(const float2*)(x + ((size_t)(og * 2) * NN + n) * 2);
    float2 x1 = *(const float2*)(x + ((size_t)(og * 2 + 1) * NN + n) * 2);
    xl[nl][og * 4 + 0] = x0.x; xl[nl][og * 4 + 1] = x0.y;
    xl[nl][og * 4 + 2] = x1.x; xl[nl][og * 4 + 3] = x1.y;
    __syncthreads();

#pragma unroll 4
    for (int b = 0; b < BB; ++b) {
        float xb0 = xl[nl][2 * b], xb1 = xl[nl][2 * b + 1];
        float yb0 = yl[nl][2 * b], yb1 = yl[nl][2 * b + 1];
        float4 o4;
        o4.x = xb0 * W[0].x + xb1 * W[1].x + yb0 * W[2].x + yb1 * W[3].x + W[4].x;
        o4.y = xb0 * W[0].y + xb1 * W[1].y + yb0 * W[2].y + yb1 * W[3].y + W[4].y;
        o4.z = xb0 * W[0].z + xb1 * W[1].z + yb0 * W[2].z + yb1 * W[3].z + W[4].z;
        o4.w = xb0 * W[0].w + xb1 * W[1].w + yb0 * W[2].w + yb1 * W[3].w + W[4].w;
        *(float4*)(out + ((size_t)b * NN + n) * HID + og * 4) = o4;
    }
}

// ---------------------------------------------------------------------------
extern "C" void kernel_launch(void* const* d_in, const int* in_sizes, int n_in,
                              void* d_out, int out_size, void* d_ws, size_t ws_size,
                              hipStream_t stream) {
    const float* x   = (const float*)d_in[0];   // [32, 8192, 2]
    const float* adj = (const float*)d_in[1];   // [8192, 16]
    const float* wp  = (const float*)d_in[2];   // [16, 2, 2, 64]
    const float* bp  = (const float*)d_in[3];   // [16, 64]
    float* out = (float*)d_out;                 // [32, 8192, 64]

    char* w = (char*)d_ws;
    short* VTf   = (short*)w;                                   // 256*4*64*16B = 1 MB
    short* Afrag = VTf + (size_t)256 * 4 * 64 * 8;              // 256*2*64*16B = 512 KB
    short* adjS  = Afrag + (size_t)256 * 2 * 64 * 8;            // 256 KB
    float* Wbuf  = (float*)(adjS + (size_t)NN * EMB);           // 10.5 MB
    short* ynum  = (short*)(Wbuf + (size_t)NN * 320);           // MS*N*64*2 = 16 MB
    float* den   = (float*)(ynum + (size_t)MS * NN * HID);      // 512 KB

    k_build<<<1024, 256, 0, stream>>>(x, adj, wp, bp, VTf, Afrag, adjS, Wbuf);
    k_prop<<<dim3(NN / 128, MS), 256, 0, stream>>>(Afrag, adjS, VTf, ynum, den);
    k_epi<<<NN / 16, 256, 0, stream>>>(Wbuf, x, ynum, den, out);
}

// Round 7
// 121.870 us; speedup vs baseline: 1.1730x; 1.0917x over previous
//
#include <hip/hip_runtime.h>

#define NN 8192
#define BB 32
#define EMB 16
#define HID 64
#define MS 16           // m-range splits

typedef __attribute__((ext_vector_type(8))) short bf16x8;
typedef __attribute__((ext_vector_type(4))) float f32x4;

static __device__ inline unsigned short f2b(float f) {   // round-to-nearest-even
    union { float f; unsigned u; } v; v.f = f;
    return (unsigned short)((v.u + 0x7fffu + ((v.u >> 16) & 1u)) >> 16);
}

// pack two fp32 (truncate) into one dword of bf16: [hi16(odd) : hi16(even)]
static __device__ inline unsigned packbf(unsigned e_even, unsigned e_odd) {
#if __has_builtin(__builtin_amdgcn_perm)
    return __builtin_amdgcn_perm(e_odd, e_even, 0x07060302u);
#else
    return (e_odd & 0xFFFF0000u) | (e_even >> 16);
#endif
}

// ---------------------------------------------------------------------------
// K1: fused operand prep (all stored in MFMA-fragment lane order).
//  bx [0,256):    VTf[c][u][lane]  : V fragments (PV A-operand)
//  bx [256,384):  Afrag[c][h][lane]: adj m-rows (score A-operand, permuted)
//  bx [384,512):  adjS[n][d] = bf16(adj*log2e)  (score B side, row-major)
//  bx [512,1024): WbufB[n][c*64+o] bf16 node-adaptive weights {x0,x1,y0,y1,b}
// ---------------------------------------------------------------------------
__global__ void k_build(const float* __restrict__ x, const float* __restrict__ adj,
                        const float* __restrict__ wp, const float* __restrict__ bp,
                        short* __restrict__ VTf, short* __restrict__ Afrag,
                        short* __restrict__ adjS, unsigned short* __restrict__ WbufB) {
    const int t = threadIdx.x;
    const int bx = blockIdx.x;
    if (bx < 256) {
        const int c = bx;
        const int u = t >> 6, lane = t & 63, l = lane & 15, q = lane >> 4;
        const int j = 16 * u + l, b = j >> 1, ch = j & 1;
        const int m0 = 32 * c + 8 * q;
        const float* xp = x + (size_t)b * (NN * 2) + m0 * 2;
        uint4 d;
        unsigned dd[4];
#pragma unroll
        for (int i = 0; i < 4; ++i) {
            float4 xx = *(const float4*)(xp + 4 * i);
            float v0 = ch ? xx.y : xx.x;
            float v1 = ch ? xx.w : xx.z;
            dd[i] = (unsigned)f2b(v0) | ((unsigned)f2b(v1) << 16);
        }
        d.x = dd[0]; d.y = dd[1]; d.z = dd[2]; d.w = dd[3];
        *(uint4*)(VTf + ((size_t)(c * 4 + u) * 64 + lane) * 8) = d;
    } else if (bx < 384) {
        const int cc = t >> 7, tt = t & 127;
        const int c = (bx - 256) * 2 + cc;
        const int h = tt >> 6, lane = tt & 63, l = lane & 15, q = lane >> 4;
        const int row = 32 * c + 8 * (l >> 2) + (l & 3) + 4 * h;
        const float* ap = adj + (size_t)row * EMB + (q & 1) * 8;
        float4 a0 = *(const float4*)(ap);
        float4 a1 = *(const float4*)(ap + 4);
        uint4 d;
        d.x = (unsigned)f2b(a0.x) | ((unsigned)f2b(a0.y) << 16);
        d.y = (unsigned)f2b(a0.z) | ((unsigned)f2b(a0.w) << 16);
        d.z = (unsigned)f2b(a1.x) | ((unsigned)f2b(a1.y) << 16);
        d.w = (unsigned)f2b(a1.z) | ((unsigned)f2b(a1.w) << 16);
        *(uint4*)(Afrag + ((size_t)(c * 2 + h) * 64 + lane) * 8) = d;
    } else if (bx < 512) {
        const float L2E = 1.4426950408889634f;
        int idx = (bx - 384) * 256 + t;
        float4 aa = *(const float4*)(adj + (size_t)idx * 4);
        uint2 us;
        us.x = (unsigned)f2b(aa.x * L2E) | ((unsigned)f2b(aa.y * L2E) << 16);
        us.y = (unsigned)f2b(aa.z * L2E) | ((unsigned)f2b(aa.w * L2E) << 16);
        *(uint2*)(adjS + (size_t)idx * 4) = us;
    } else {
        const int nl = t >> 4, og = t & 15;
        const int n = (bx - 512) * 16 + nl;
        const float4* wp4 = (const float4*)wp;
        const float4* bp4 = (const float4*)bp;
        float an[EMB];
#pragma unroll
        for (int d = 0; d < EMB; ++d) an[d] = adj[n * EMB + d];
        float4 w[5];
#pragma unroll
        for (int c = 0; c < 5; ++c) { w[c].x = w[c].y = w[c].z = w[c].w = 0.f; }
#pragma unroll
        for (int d = 0; d < EMB; ++d) {
            float a = an[d];
#pragma unroll
            for (int c = 0; c < 4; ++c) {
                float4 p = wp4[(d * 4 + c) * 16 + og];
                w[c].x += a * p.x; w[c].y += a * p.y; w[c].z += a * p.z; w[c].w += a * p.w;
            }
            float4 pb = bp4[d * 16 + og];
            w[4].x += a * pb.x; w[4].y += a * pb.y; w[4].z += a * pb.z; w[4].w += a * pb.w;
        }
#pragma unroll
        for (int c = 0; c < 5; ++c) {
            ushort4 pk;
            pk.x = f2b(w[c].x); pk.y = f2b(w[c].y); pk.z = f2b(w[c].z); pk.w = f2b(w[c].w);
            *(ushort4*)(WbufB + (size_t)n * 320 + c * 64 + og * 4) = pk;
        }
    }
}

// ---------------------------------------------------------------------------
// K2: MFMA flash propagation with explicit 1-deep ping-pong prefetch.
// 4 waves/block, 32 n per wave, barrier/LDS/atomic-free. bf16 partials out.
// ---------------------------------------------------------------------------
__launch_bounds__(256, 3)
__global__ void k_prop(const short* __restrict__ Afrag, const short* __restrict__ adjS,
                       const short* __restrict__ VTf,
                       short* __restrict__ ynum, float* __restrict__ den) {
    const int t = threadIdx.x;
    const int wv = t >> 6;
    const int lane = t & 63;
    const int l = lane & 15;
    const int q = lane >> 4;
    const int n0 = blockIdx.x * 128 + wv * 32;
    const int cbeg = blockIdx.y * (NN / MS / 32);   // 16 c-subtiles per block
    const int cend = cbeg + (NN / MS / 32);

    // loop-invariant score B-fragments (log2e-scaled), k>=16 zeroed
    bf16x8 Bn[2];
    bf16x8 zv = {0, 0, 0, 0, 0, 0, 0, 0};
#pragma unroll
    for (int s = 0; s < 2; ++s) {
        const short* src = adjS + (size_t)(n0 + 16 * s + l) * EMB + (q & 1) * 8;
        bf16x8 v = *(const bf16x8*)src;
        Bn[s] = (q < 2) ? v : zv;
    }
    const short one = (short)0x3F80;
    bf16x8 ones = {one, one, one, one, one, one, one, one};

    f32x4 acc[4][2];
    f32x4 dacc[2];
#pragma unroll
    for (int u = 0; u < 4; ++u)
#pragma unroll
        for (int s = 0; s < 2; ++s) { acc[u][s][0] = acc[u][s][1] = acc[u][s][2] = acc[u][s][3] = 0.f; }
#pragma unroll
    for (int s = 0; s < 2; ++s) { dacc[s][0] = dacc[s][1] = dacc[s][2] = dacc[s][3] = 0.f; }

    const short* Ap = Afrag + (size_t)lane * 8;   // + cg*1024 + h*512
    const short* Vp = VTf + (size_t)lane * 8;     // + cg*2048 + u*512

#define LOADF(cg, a0, a1, vv)                                            \
    do {                                                                 \
        a0 = *(const bf16x8*)(Ap + (size_t)(cg) * 1024);                 \
        a1 = *(const bf16x8*)(Ap + (size_t)(cg) * 1024 + 512);           \
        vv[0] = *(const bf16x8*)(Vp + (size_t)(cg) * 2048);              \
        vv[1] = *(const bf16x8*)(Vp + (size_t)(cg) * 2048 + 512);        \
        vv[2] = *(const bf16x8*)(Vp + (size_t)(cg) * 2048 + 1024);       \
        vv[3] = *(const bf16x8*)(Vp + (size_t)(cg) * 2048 + 1536);       \
    } while (0)

    auto compute = [&](bf16x8 Af0, bf16x8 Af1, bf16x8* Vf) {
        f32x4 z = {0.f, 0.f, 0.f, 0.f};
        f32x4 S0[2], S1[2];
#pragma unroll
        for (int s = 0; s < 2; ++s) {
            S0[s] = __builtin_amdgcn_mfma_f32_16x16x32_bf16(Af0, Bn[s], z, 0, 0, 0);
            S1[s] = __builtin_amdgcn_mfma_f32_16x16x32_bf16(Af1, Bn[s], z, 0, 0, 0);
        }
#pragma unroll
        for (int s = 0; s < 2; ++s) {
            unsigned w0[4], w1[4];
#pragma unroll
            for (int r = 0; r < 4; ++r) {
                union { float f; unsigned u; } p0, p1;
                p0.f = __builtin_amdgcn_exp2f(fmaxf(S0[s][r], 0.f));
                p1.f = __builtin_amdgcn_exp2f(fmaxf(S1[s][r], 0.f));
                w0[r] = p0.u;      // j = r      (h=0)
                w1[r] = p1.u;      // j = 4 + r  (h=1)
            }
            union { bf16x8 v; unsigned d[4]; } pf;
            pf.d[0] = packbf(w0[0], w0[1]);
            pf.d[1] = packbf(w0[2], w0[3]);
            pf.d[2] = packbf(w1[0], w1[1]);
            pf.d[3] = packbf(w1[2], w1[3]);
#pragma unroll
            for (int u = 0; u < 4; ++u)
                acc[u][s] = __builtin_amdgcn_mfma_f32_16x16x32_bf16(Vf[u], pf.v, acc[u][s], 0, 0, 0);
            dacc[s] = __builtin_amdgcn_mfma_f32_16x16x32_bf16(ones, pf.v, dacc[s], 0, 0, 0);
        }
    };

    bf16x8 a0A, a1A, vA[4], a0B, a1B, vB[4];
    LOADF(cbeg, a0A, a1A, vA);
    for (int cg = cbeg; cg < cend; cg += 2) {
        LOADF(cg + 1, a0B, a1B, vB);          // prefetch odd tile
        compute(a0A, a1A, vA);                // compute even tile (loads long done)
        int cg2 = (cg + 2 < cend) ? cg + 2 : cbeg;   // clamped redundant last load
        LOADF(cg2, a0A, a1A, vA);             // prefetch next even tile
        compute(a0B, a1B, vB);                // compute odd tile
    }
#undef LOADF

    // stores: bf16 partials [split][n][64]; den rows all equal -> dacc[s][0]
    short* yp = ynum + (size_t)blockIdx.y * NN * HID;
#pragma unroll
    for (int s = 0; s < 2; ++s) {
        const int n = n0 + 16 * s + l;
#pragma unroll
        for (int u = 0; u < 4; ++u) {
            union { float f; unsigned u; } a0, a1, a2, a3;
            a0.f = acc[u][s][0]; a1.f = acc[u][s][1]; a2.f = acc[u][s][2]; a3.f = acc[u][s][3];
            uint2 pk;
            pk.x = packbf(a0.u, a1.u);
            pk.y = packbf(a2.u, a3.u);
            *(uint2*)(yp + (size_t)n * HID + 16 * u + 4 * q) = pk;
        }
        if (q == 0) den[(size_t)blockIdx.y * NN + n] = dacc[s][0];
    }
}

// ---------------------------------------------------------------------------
// K3: epilogue. 16 nodes/block; reduce MS bf16 partials, normalize, apply
// bf16 per-node weights, nontemporal write out [32][8192][64] fp32.
// ---------------------------------------------------------------------------
__global__ void k_epi(const unsigned short* __restrict__ WbufB, const float* __restrict__ x,
                      const short* __restrict__ ynum, const float* __restrict__ den,
                      float* __restrict__ out) {
    const int nl = threadIdx.x >> 4, og = threadIdx.x & 15;
    const int n = blockIdx.x * 16 + nl;
    __shared__ float xl[16][68];
    __shared__ float yl[16][68];

    float4 W[5];
#pragma unroll
    for (int c = 0; c < 5; ++c) {
        ushort4 pw = *(const ushort4*)(WbufB + (size_t)n * 320 + c * 64 + og * 4);
        union { unsigned u; float f; } c0, c1, c2, c3;
        c0.u = (unsigned)pw.x << 16; c1.u = (unsigned)pw.y << 16;
        c2.u = (unsigned)pw.z << 16; c3.u = (unsigned)pw.w << 16;
        W[c].x = c0.f; W[c].y = c1.f; W[c].z = c2.f; W[c].w = c3.f;
    }

    float4 ysum; ysum.x = ysum.y = ysum.z = ysum.w = 0.f;
    float dsum = 0.f;
#pragma unroll
    for (int s = 0; s < MS; ++s) {
        ushort4 p = *(const ushort4*)(ynum + ((size_t)s * NN + n) * HID + og * 4);
        union { unsigned u; float f; } c0, c1, c2, c3;
        c0.u = (unsigned)p.x << 16; c1.u = (unsigned)p.y << 16;
        c2.u = (unsigned)p.z << 16; c3.u = (unsigned)p.w << 16;
        ysum.x += c0.f; ysum.y += c1.f; ysum.z += c2.f; ysum.w += c3.f;
        dsum += den[(size_t)s * NN + n];
    }
    float rden = 1.f / dsum;
    *(float4*)&yl[nl][og * 4] = make_float4(ysum.x * rden, ysum.y * rden, ysum.z * rden, ysum.w * rden);

    float2 x0 = *(const float2*)(x + ((size_t)(og * 2) * NN + n) * 2);
    float2 x1 = *(const float2*)(x + ((size_t)(og * 2 + 1) * NN + n) * 2);
    xl[nl][og * 4 + 0] = x0.x; xl[nl][og * 4 + 1] = x0.y;
    xl[nl][og * 4 + 2] = x1.x; xl[nl][og * 4 + 3] = x1.y;
    __syncthreads();

#pragma unroll 4
    for (int b = 0; b < BB; ++b) {
        float xb0 = xl[nl][2 * b], xb1 = xl[nl][2 * b + 1];
        float yb0 = yl[nl][2 * b], yb1 = yl[nl][2 * b + 1];
        f32x4 o4;
        o4[0] = xb0 * W[0].x + xb1 * W[1].x + yb0 * W[2].x + yb1 * W[3].x + W[4].x;
        o4[1] = xb0 * W[0].y + xb1 * W[1].y + yb0 * W[2].y + yb1 * W[3].y + W[4].y;
        o4[2] = xb0 * W[0].z + xb1 * W[1].z + yb0 * W[2].z + yb1 * W[3].z + W[4].z;
        o4[3] = xb0 * W[0].w + xb1 * W[1].w + yb0 * W[2].w + yb1 * W[3].w + W[4].w;
        __builtin_nontemporal_store(o4, (f32x4*)(out + ((size_t)b * NN + n) * HID + og * 4));
    }
}

// ---------------------------------------------------------------------------
extern "C" void kernel_launch(void* const* d_in, const int* in_sizes, int n_in,
                              void* d_out, int out_size, void* d_ws, size_t ws_size,
                              hipStream_t stream) {
    const float* x   = (const float*)d_in[0];   // [32, 8192, 2]
    const float* adj = (const float*)d_in[1];   // [8192, 16]
    const float* wp  = (const float*)d_in[2];   // [16, 2, 2, 64]
    const float* bp  = (const float*)d_in[3];   // [16, 64]
    float* out = (float*)d_out;                 // [32, 8192, 64]

    char* w = (char*)d_ws;
    short* VTf   = (short*)w;                                   // 1 MB
    short* Afrag = VTf + (size_t)256 * 4 * 64 * 8;              // 512 KB
    short* adjS  = Afrag + (size_t)256 * 2 * 64 * 8;            // 256 KB
    unsigned short* WbufB = (unsigned short*)(adjS + (size_t)NN * EMB);  // 5.25 MB
    short* ynum  = (short*)(WbufB + (size_t)NN * 320);          // 16 MB
    float* den   = (float*)(ynum + (size_t)MS * NN * HID);      // 512 KB

    k_build<<<1024, 256, 0, stream>>>(x, adj, wp, bp, VTf, Afrag, adjS, WbufB);
    k_prop<<<dim3(NN / 128, MS), 256, 0, stream>>>(Afrag, adjS, VTf, ynum, den);
    k_epi<<<NN / 16, 256, 0, stream>>>(WbufB, x, ynum, den, out);
}